// Round 9
// baseline (243.394 us; speedup 1.0000x reference)
//
#include <hip/hip_runtime.h>
#include <math.h>

typedef unsigned short u16;
typedef __attribute__((ext_vector_type(8))) short short8;   // 8 bf16 operand frag (4 VGPRs)
typedef __attribute__((ext_vector_type(4))) float floatx4;  // 4 fp32 accum frag

#define LDS_AS(p) ((__attribute__((address_space(3))) void*)(p))
#define GLB_AS(p) ((const __attribute__((address_space(1))) void*)(p))

__device__ __forceinline__ u16 f2bf(float f) {
  unsigned int u = __float_as_uint(f);
  u += 0x7fffu + ((u >> 16) & 1u);          // round-to-nearest-even
  return (u16)(u >> 16);
}

__device__ __forceinline__ void gld16(const void* g, void* l) {
  // async global->LDS, 16B/lane, dest = wave-uniform base + lane*16
  __builtin_amdgcn_global_load_lds(GLB_AS(g), LDS_AS(l), 16, 0, 0);
}

__device__ __forceinline__ floatx4 mfma16(short8 a, short8 b, floatx4 c) {
  return __builtin_amdgcn_mfma_f32_16x16x32_bf16(a, b, c, 0, 0, 0);
}

// PANE CONVENTION: a pane is 512 u16 = [16 rows][32 cols] in MFMA lane order,
// element (lane,j) = src[row0 + (lane&15)][col0 + (lane>>4)*8 + j]. One
// gld16/store per pane is a single contiguous 1KB burst. Tensors:
//   qb,kb : [bh][chk16][nsub8][kk2][512]   kwt: [bh][chk16][m4][kst4][512]
//   vtb   : [bh][chk16][jd4][kst4][512]    Sb : [bh][chk16][nd4][kk2][512]

// ---------------------------------------------------------------- fused prep
__global__ void prep_kernel(const float* __restrict__ x, const float* __restrict__ Wq,
                            const float* __restrict__ Wk, const float* __restrict__ Wv,
                            const float* __restrict__ Wo, u16* __restrict__ xp,
                            u16* __restrict__ wqkvp, u16* __restrict__ wop,
                            float2* __restrict__ rtab) {
  int i = blockIdx.x * blockDim.x + threadIdx.x;
  const int str = gridDim.x * blockDim.x;
  for (; i < 3211264; i += str) {
    if (i < 3145728) {
      // one ushort4 (4 dest u16, same lane, j-half jh) per iteration
      int U; u16* d;
      const float* s;
      if (i < 2097152)      { U = i;           d = xp;    s = x;  }
      else if (i < 2883584) { U = i - 2097152; d = wqkvp; s = nullptr; }
      else                  { U = i - 2883584; d = wop;   s = Wo; }
      const int tile = U >> 12;            // 16-row tile
      const int kc   = (U >> 7) & 31;      // 32-col chunk
      const int lane = (U >> 1) & 63;
      const int jh   = U & 1;
      const int scol = kc * 32 + (lane >> 4) * 8 + jh * 4;
      int srow = tile * 16 + (lane & 15);
      if (s == nullptr) {                  // stacked Wq/Wk/Wv rows
        const int sel = srow >> 10;
        srow &= 1023;
        s = (sel == 0) ? Wq : (sel == 1) ? Wk : Wv;
      }
      float4 v = ((const float4*)s)[srow * 256 + (scol >> 2)];
      ushort4 o;
      o.x = f2bf(v.x); o.y = f2bf(v.y); o.z = f2bf(v.z); o.w = f2bf(v.w);
      ((ushort4*)d)[U] = o;
    } else {
      const int t = i - 3145728;              // 0..65535
      const int seq = t >> 5, dh = t & 31;
      const float freq = exp2f(-(float)dh * 0.42863594770f); // log2(1e4)/31
      float sn, cs;
      __sincosf((float)seq * freq, &sn, &cs);
      rtab[t] = make_float2(sn, cs);
    }
  }
}

// ---------------------------------------------------------------- GEMM C = A * B^T
// Geometry = round-7/8 verified (128x256 QKV / BM=64 out, BK=32, 4 waves,
// 3x24KB bufs, depth-2, counted vmcnt, 2 blocks/CU, pane-packed operands).
// ROUND-9 CHANGE (m201 phase ordering, the one untested element): per K-step
//   [ds_read(t) -> stage(t+2) -> vmcnt(6|5) -> s_barrier ->
//    lgkmcnt(0)+sched_barrier -> setprio/MFMA/setprio -> s_barrier]
// ds_reads and stage now issue BEFORE the barrier pair, so their latency
// overlaps other waves' MFMA region; the dual barrier creates the wave
// role-split that makes setprio/counted-vmcnt pay (m218/m224).
// Race ledger: ds(t) reads buf published by step t-1's vmcnt+BAR1; stage(t+2)
// writes buf[(t-1)%3] whose reads completed (lgkm(0) precedes MFMA(t-1)
// precedes BAR2(t-1)) and issues after BAR2(t-1); vmcnt(6) leaves only
// t+2's 6 loads outstanding (in-order retirement, m135).
template <int EPI>
__global__ __launch_bounds__(256, 2)
void gemm_bt(const u16* __restrict__ A, const u16* __restrict__ Bw, int K,
             u16* __restrict__ qb, u16* __restrict__ kb, u16* __restrict__ vtb,
             u16* __restrict__ kwt, const float2* __restrict__ rtab,
             float* __restrict__ outp) {
  constexpr int AP   = (EPI == 0) ? 8 : 4;        // A panes per buffer
  constexpr int BUFU = (AP + 16) * 512;           // u16 per buffer
  constexpr int AOFF = AP * 512;                  // B area offset in buffer
  constexpr int AI   = (EPI == 0) ? 8 : 4;        // acc rows (16-row frags)
  constexpr int IH   = (EPI == 0) ? 2 : 1;        // epilogue 64-row halves
  __shared__ __align__(16) u16 smem[3 * 12288];   // 72 KB worst case
  const int tid = threadIdx.x;
  const int w = tid >> 6, lane = tid & 63;        // 4 waves
  const int quad = lane >> 4, l15 = lane & 15;
  const int m0 = blockIdx.y * (EPI == 0 ? 128 : 64), n0 = blockIdx.x * 256;

  const size_t tsz = (size_t)(K >> 5) * 512;       // u16 per packed 16-row tile
  const u16* A0 = A + ((size_t)(m0 >> 4) + (EPI == 0 ? 2 * w : w)) * tsz + lane * 8;
  const u16* A1 = A0 + tsz;                        // used only when EPI==0
  const u16* Bb = Bw + ((size_t)(n0 >> 4) + 4 * w) * tsz + lane * 8;

  auto stage = [&](int buf, int kc) {
    const int nb = buf * BUFU;
    gld16(A0 + (size_t)kc * 512, &smem[nb + (EPI == 0 ? 2 * w : w) * 512]);
    if constexpr (EPI == 0)
      gld16(A1 + (size_t)kc * 512, &smem[nb + (2 * w + 1) * 512]);
#pragma unroll
    for (int e = 0; e < 4; ++e)
      gld16(Bb + (size_t)e * tsz + (size_t)kc * 512,
            &smem[nb + AOFF + (4 * w + e) * 512]);
  };

  floatx4 acc[AI][4] = {};
  const int NT = K >> 5;                      // 32 K-steps (pane index = step)

  stage(0, 0);                                // prologue: tiles 0,1 in flight
  stage(1, 1);
  if constexpr (EPI == 0)                     // tile 0 landed; tile 1 in flight
    asm volatile("s_waitcnt vmcnt(6)" ::: "memory");
  else
    asm volatile("s_waitcnt vmcnt(5)" ::: "memory");
  __builtin_amdgcn_s_barrier();               // publish tile 0

  int cur = 0, stg = 2;
  for (int t = 0; t < NT; ++t) {
    // --- phase: ds_read current tile (issued pre-barrier, consumed post-lgkm)
    const u16* Ap = &smem[cur * BUFU];
    const u16* Bp = Ap + AOFF;
    short8 a[AI], b[4];
#pragma unroll
    for (int i = 0; i < AI; ++i)
      a[i] = *(const short8*)&Ap[i * 512 + lane * 8];
#pragma unroll
    for (int j = 0; j < 4; ++j)
      b[j] = *(const short8*)&Bp[(w * 4 + j) * 512 + lane * 8];
    // --- stage tile t+2 (depth-2), then counted wait guarding tile t+1
    if (t + 2 < NT) {
      stage(stg, t + 2);
      if constexpr (EPI == 0)
        asm volatile("s_waitcnt vmcnt(6)" ::: "memory");
      else
        asm volatile("s_waitcnt vmcnt(5)" ::: "memory");
    } else {
      asm volatile("s_waitcnt vmcnt(0)" ::: "memory");
    }
    __builtin_amdgcn_s_barrier();             // BAR1: publish t+1, align waves
    asm volatile("s_waitcnt lgkmcnt(0)" ::: "memory");
    __builtin_amdgcn_sched_barrier(0);        // rule #18: pin MFMA after lgkm
    __builtin_amdgcn_s_setprio(1);
#pragma unroll
    for (int i = 0; i < AI; ++i)
#pragma unroll
      for (int j = 0; j < 4; ++j)
        acc[i][j] = mfma16(a[i], b[j], acc[i][j]);
    __builtin_amdgcn_s_setprio(0);
    asm volatile("" ::: "memory");
    __builtin_amdgcn_s_barrier();             // BAR2: close phase
    asm volatile("" ::: "memory");
    cur = (cur == 2) ? 0 : cur + 1;
    stg = (stg == 2) ? 0 : stg + 1;
  }

  // staging LDS now dead -> 8 KB wave-private scratch (4 waves x 8 KB = 32 KB)
  u16* scr = &smem[w * 4096];

  const int ncb = n0 + w * 64;

#pragma unroll
  for (int ih = 0; ih < IH; ++ih) {
    const int mrb = m0 + ih * 64;

    if (EPI == 0) {
      const int which = n0 >> 10;       // 0:q 1:k 2:v  (256-col blocks, 4 per matrix)
      const int c1024 = ncb & 1023;
      const int bidx = mrb >> 11;
      const int hh = c1024 >> 6;        // wave-tile col-quarter = one head (64 d)
      const int seq0 = mrb & 2047;
      const int chk = seq0 >> 7;        // 128-seq chunk; s-in-chunk base = ih*64

      if (which < 2) {
        // ---- pass 1: q/k, RoPE applied, rotated d-chunks in scr [sl][d-rot]
#pragma unroll
        for (int j = 0; j < 4; ++j) {
          const int d = j * 16 + l15;
          const int dc = d >> 3, dl = d & 7;
#pragma unroll
          for (int i = 0; i < 4; ++i)
#pragma unroll
            for (int r = 0; r < 4; ++r) {
              const int sl = i * 16 + quad * 4 + r;
              const int seq = seq0 + sl;
              const float v = acc[ih * 4 + i][j][r];
              const float p = __shfl_xor(v, 1, 64);
              const float2 sc = rtab[(d >> 1) + seq * 32];
              const float res = (d & 1) ? (v * sc.y + p * sc.x) : (v * sc.y - p * sc.x);
              scr[sl * 64 + (((dc + (sl >> 2)) & 7) << 3) + dl] = f2bf(res);
            }
        }
        // pane stores: [bh][chk][nsub][kk][512], 8 x 1KB contiguous bursts
        u16* dst = ((which == 0) ? qb : kb) +
                   (((size_t)(bidx * 16 + hh) * 16 + chk) << 13);
#pragma unroll
        for (int nl = 0; nl < 4; ++nl)
#pragma unroll
          for (int kk2 = 0; kk2 < 2; ++kk2) {
            const int slr = nl * 16 + l15;
            const int slot = ((kk2 * 4 + quad) + (slr >> 2)) & 7;
            short8 vv = *(const short8*)&scr[slr * 64 + slot * 8];
            *(short8*)(dst + (((ih * 4 + nl) * 2 + kk2) * 512) + lane * 8) = vv;
          }
        if (which == 1) {
          // ---- pass 2: kwt panes [bh][chk][m][kst][512], decay-weighted
          const float l2h = __log2f(1.0f - exp2f(-(float)(5 + hh)));
#pragma unroll
          for (int j = 0; j < 4; ++j) {
            const int d = j * 16 + l15;
#pragma unroll
            for (int i = 0; i < 4; ++i) {
              ushort4 pk;
#pragma unroll
              for (int r = 0; r < 4; ++r) {
                const int sl = i * 16 + quad * 4 + r;
                const int seq = seq0 + sl;
                const float v = acc[ih * 4 + i][j][r];
                const float p = __shfl_xor(v, 1, 64);
                const float2 sc = rtab[(d >> 1) + seq * 32];
                const float res = (d & 1) ? (v * sc.y + p * sc.x) : (v * sc.y - p * sc.x);
                const float wgt = exp2f((float)(127 - (seq & 127)) * l2h);
                ((u16*)&pk)[r] = f2bf(res * wgt);
              }
              *(ushort4*)&scr[d * 64 + ((i * 16 + quad * 4 + 8 * (d & 7)) & 63)] = pk;
            }
          }
          u16* dw = kwt + (((size_t)(bidx * 16 + hh) * 16 + chk) << 13);
#pragma unroll
          for (int m = 0; m < 4; ++m)
#pragma unroll
            for (int ks2 = 0; ks2 < 2; ++ks2) {
              const int dr = m * 16 + l15;
              const int col = ((ks2 * 32 + quad * 8) + 8 * (dr & 7)) & 63;
              short8 vv = *(const short8*)&scr[dr * 64 + col];
              *(short8*)(dw + ((m * 4 + ih * 2 + ks2) * 512) + lane * 8) = vv;
            }
        }
      } else {
        // ---- v transposed panes [bh][chk][jd][kst][512]
#pragma unroll
        for (int j = 0; j < 4; ++j) {
          const int d = j * 16 + l15;
#pragma unroll
          for (int i = 0; i < 4; ++i) {
            ushort4 pk;
            pk.x = f2bf(acc[ih * 4 + i][j][0]);
            pk.y = f2bf(acc[ih * 4 + i][j][1]);
            pk.z = f2bf(acc[ih * 4 + i][j][2]);
            pk.w = f2bf(acc[ih * 4 + i][j][3]);
            *(ushort4*)&scr[d * 64 + ((i * 16 + quad * 4 + 8 * (d & 7)) & 63)] = pk;
          }
        }
        u16* dh = vtb + (((size_t)(bidx * 16 + hh) * 16 + chk) << 13);
#pragma unroll
        for (int m = 0; m < 4; ++m)
#pragma unroll
          for (int ks2 = 0; ks2 < 2; ++ks2) {
            const int dr = m * 16 + l15;
            const int col = ((ks2 * 32 + quad * 8) + 8 * (dr & 7)) & 63;
            short8 vv = *(const short8*)&scr[dr * 64 + col];
            *(short8*)(dh + ((m * 4 + ih * 2 + ks2) * 512) + lane * 8) = vv;
          }
      }
    } else {
      // ---- fp32 out via LDS quarter-tiles (16 rows x pitch 65), full-line stores
      float* scrf = (float*)scr;                  // 8 KB = 2048 fp32
      const int lr4 = lane >> 4, lc16 = lane & 15;
#pragma unroll
      for (int p = 0; p < 4; ++p) {               // p = row-group (acc i index)
#pragma unroll
        for (int j = 0; j < 4; ++j)
#pragma unroll
          for (int r = 0; r < 4; ++r)
            scrf[(quad * 4 + r) * 65 + j * 16 + l15] = acc[p][j][r];
#pragma unroll
        for (int cch = 0; cch < 4; ++cch) {       // 4 stores x 4 rows x 256 B
          const int rr = cch * 4 + lr4;
          float4 vv = *(const float4*)&scrf[rr * 65 + lc16 * 4];
          *(float4*)&outp[(size_t)(mrb + p * 16 + rr) * 1024 + ncb + lc16 * 4] = vv;
        }
      }
    }
  }
}

// ---------------------------------------------------------------- chunk KV: U_c = sum_t w_t k_t v_t^T
__global__ __launch_bounds__(256, 4)
void kvchunk_kernel(const u16* __restrict__ kwt, const u16* __restrict__ vtb,
                    float* __restrict__ U) {
  __shared__ __align__(16) u16 kls[16 * 512];
  __shared__ __align__(16) u16 vls[16 * 512];
  const int c = blockIdx.x, bh = blockIdx.y;
  const int tid = threadIdx.x, w = tid >> 6, lane = tid & 63;
  const int quad = lane >> 4, l15 = lane & 15;
  // pane-contiguous staging: 1KB burst per gld16
  const u16* kg = kwt + (((size_t)bh * 16 + c) << 13);
  const u16* vg = vtb + (((size_t)bh * 16 + c) << 13);
#pragma unroll
  for (int rg = 0; rg < 4; ++rg) {
    const int rid = w * 4 + rg;               // pane idx == LDS region idx
    gld16(kg + rid * 512 + lane * 8, &kls[rid * 512]);
    gld16(vg + rid * 512 + lane * 8, &vls[rid * 512]);
  }
  __syncthreads();
  floatx4 acc[4] = {};
#pragma unroll
  for (int kst = 0; kst < 4; ++kst) {
    short8 bf = *(const short8*)&vls[(w * 4 + kst) * 512 + lane * 8];
#pragma unroll
    for (int m = 0; m < 4; ++m) {
      short8 af = *(const short8*)&kls[(m * 4 + kst) * 512 + lane * 8];
      acc[m] = mfma16(af, bf, acc[m]);
    }
  }
  float* Ub = U + ((size_t)bh * 16 + c) * 4096;
#pragma unroll
  for (int m = 0; m < 4; ++m)
#pragma unroll
    for (int r = 0; r < 4; ++r)
      Ub[(m * 16 + quad * 4 + r) * 64 + w * 16 + l15] = acc[m][r];
}

// ---------------------------------------------------------------- state scan
// 64 blocks x 4 waves: wave w owns dk-quarter [w*16, w*16+16), lane = dv.
// Sb written PANE-PACKED: [bh][chk][nd][kk][512].
__global__ void scan_kernel(const float* __restrict__ U, u16* __restrict__ Sb) {
  const int bh = blockIdx.x;
  const int w = threadIdx.x >> 6, l = threadIdx.x & 63;
  const int h = bh & 15;
  const float l2 = __log2f(1.0f - exp2f(-(float)(5 + h)));
  const float lamL = exp2f(128.0f * l2);
  float S[16];
#pragma unroll
  for (int i = 0; i < 16; ++i) S[i] = 0.f;
  for (int c = 0; c < 16; ++c) {
    u16* sp = Sb + (((size_t)bh * 16 + c) << 12);
#pragma unroll
    for (int g = 0; g < 2; ++g) {            // dk' groups 0-7, 8-15
      short8 pk;
#pragma unroll
      for (int j = 0; j < 8; ++j) ((u16*)&pk)[j] = f2bf(S[g * 8 + j]);
      const int lp = ((w & 1) * 2 + g) * 16 + (l & 15);   // lane-in-pane
      *(short8*)(sp + (((l >> 4) * 2 + (w >> 1)) * 512) + lp * 8) = pk;
    }
    const float* up = U + ((size_t)bh * 16 + c) * 4096 + (w * 16) * 64 + l;
#pragma unroll
    for (int dk = 0; dk < 16; ++dk)
      S[dk] = lamL * S[dk] + up[dk * 64];
  }
}

// ---------------------------------------------------------------- chunked attention
__global__ __launch_bounds__(256, 2)
void attn_chunk_kernel(const u16* __restrict__ qb, const u16* __restrict__ kb,
                       const u16* __restrict__ vtb, const u16* __restrict__ Sb,
                       const float* __restrict__ lnw, const float* __restrict__ lnb,
                       u16* __restrict__ yb) {
  __shared__ __align__(16) u16 kls[16 * 512];
  __shared__ __align__(16) u16 vls[16 * 512];
  __shared__ __align__(16) u16 Sls[8 * 512];
  __shared__ __align__(16) u16 pls[4 * 32 * 40];   // per-wave quarter P strip, pitch 40

  const int c = blockIdx.x, bh = blockIdx.y, h = bh & 15;
  const int tid = threadIdx.x;
  const int w = tid >> 6, lane = tid & 63, quad = lane >> 4, l15 = lane & 15;
  const float l2 = __log2f(1.0f - exp2f(-(float)(5 + h)));

  // pane-contiguous staging: pane idx == LDS region idx, 1KB burst each
  const u16* kg = kb + (((size_t)bh * 16 + c) << 13);
  const u16* vg = vtb + (((size_t)bh * 16 + c) << 13);
  const u16* Sg = Sb + (((size_t)bh * 16 + c) << 12);
#pragma unroll
  for (int rg = 0; rg < 4; ++rg) {
    const int kid = w * 4 + rg;
    gld16(kg + kid * 512 + lane * 8, &kls[kid * 512]);
    gld16(vg + kid * 512 + lane * 8, &vls[kid * 512]);
  }
#pragma unroll
  for (int e = 0; e < 2; ++e) {
    const int rid = w * 2 + e;
    gld16(Sg + rid * 512 + lane * 8, &Sls[rid * 512]);
  }

  // q fragments: direct pane register loads (contiguous 1KB per fragment)
  short8 qf[2][2];
  {
    const u16* qp = qb + (((size_t)bh * 16 + c) << 13);
#pragma unroll
    for (int i = 0; i < 2; ++i)
#pragma unroll
      for (int kk = 0; kk < 2; ++kk)
        qf[i][kk] = *(const short8*)(qp + (((w * 2 + i) * 2 + kk) * 512) + lane * 8);
  }
  float lnwv[4], lnbv[4];
#pragma unroll
  for (int jd = 0; jd < 4; ++jd) {
    lnwv[jd] = lnw[jd * 16 + l15];
    lnbv[jd] = lnb[jd * 16 + l15];
  }
  __syncthreads();

  // ---- intra scores: S = q k^T (32 s-rows x 128 t-cols)
  floatx4 sacc[2][8] = {};
#pragma unroll
  for (int kk = 0; kk < 2; ++kk) {
    short8 bf[8];
#pragma unroll
    for (int j = 0; j < 8; ++j)
      bf[j] = *(const short8*)&kls[(j * 2 + kk) * 512 + lane * 8];
#pragma unroll
    for (int i = 0; i < 2; ++i)
#pragma unroll
      for (int j = 0; j < 8; ++j)
        sacc[i][j] = mfma16(qf[i][kk], bf[j], sacc[i][j]);
  }

  // ---- cross: oacc = q . S_state^T, scaled by lambda^{s_loc+1}
  floatx4 oacc[2][4] = {};
#pragma unroll
  for (int kk = 0; kk < 2; ++kk)
#pragma unroll
    for (int nd = 0; nd < 4; ++nd) {
      short8 sf = *(const short8*)&Sls[(nd * 2 + kk) * 512 + lane * 8];
#pragma unroll
      for (int i = 0; i < 2; ++i)
        oacc[i][nd] = mfma16(qf[i][kk], sf, oacc[i][nd]);
    }
  float rowf[8];
#pragma unroll
  for (int i = 0; i < 2; ++i)
#pragma unroll
    for (int r = 0; r < 4; ++r)
      rowf[i * 4 + r] = exp2f((float)(w * 32 + i * 16 + quad * 4 + r) * l2);
  const float lam1 = exp2f(l2);
#pragma unroll
  for (int i = 0; i < 2; ++i)
#pragma unroll
    for (int nd = 0; nd < 4; ++nd)
#pragma unroll
      for (int r = 0; r < 4; ++r)
        oacc[i][nd][r] *= rowf[i * 4 + r] * lam1;   // lambda^{s_loc+1}

  // ---- intra PV with masked/decayed P, quarter-strip at a time
  float colf[8];
#pragma unroll
  for (int j = 0; j < 8; ++j) colf[j] = exp2f(-(float)(j * 16 + l15) * l2);
  u16* pw = &pls[w * 1280];
#pragma unroll
  for (int kst = 0; kst < 4; ++kst) {
#pragma unroll
    for (int jl = 0; jl < 2; ++jl) {
      const int j = kst * 2 + jl;
#pragma unroll
      for (int i = 0; i < 2; ++i)
#pragma unroll
        for (int r = 0; r < 4; ++r) {
          const int srow = i * 16 + quad * 4 + r;            // wave-local s
          const int dlt = (w * 32 + srow) - (j * 16 + l15);  // causal in-chunk
          const float v =
              (dlt >= 0) ? sacc[i][j][r] * rowf[i * 4 + r] * colf[j] : 0.0f;
          pw[srow * 40 + jl * 16 + l15] = f2bf(v);
        }
    }
    short8 pf[2], vf[4];
#pragma unroll
    for (int i = 0; i < 2; ++i)
      pf[i] = *(const short8*)&pw[(i * 16 + l15) * 40 + quad * 8];
#pragma unroll
    for (int jd = 0; jd < 4; ++jd)
      vf[jd] = *(const short8*)&vls[(jd * 4 + kst) * 512 + lane * 8];
#pragma unroll
    for (int i = 0; i < 2; ++i)
#pragma unroll
      for (int jd = 0; jd < 4; ++jd)
        oacc[i][jd] = mfma16(pf[i], vf[jd], oacc[i][jd]);
  }

  // ---- LayerNorm(64) + SiLU -> y, PANE-PACKED via LDS transpose.
  __syncthreads();
  u16* scrw = &kls[w * 2048];                  // 32 rows x 64 f, rotated chunks
  const int b = bh >> 4;
#pragma unroll
  for (int i = 0; i < 2; ++i)
#pragma unroll
    for (int r = 0; r < 4; ++r) {
      float sum = 0.f, ssq = 0.f;
#pragma unroll
      for (int jd = 0; jd < 4; ++jd) {
        const float v = oacc[i][jd][r];
        sum += v;
        ssq += v * v;
      }
#pragma unroll
      for (int off = 1; off < 16; off <<= 1) {
        sum += __shfl_xor(sum, off, 64);
        ssq += __shfl_xor(ssq, off, 64);
      }
      const float mu = sum * (1.0f / 64.0f);
      const float var = ssq * (1.0f / 64.0f) - mu * mu;
      const float rst = rsqrtf(var + 1e-5f);
      const int sl = i * 16 + quad * 4 + r;    // wave-local token row
#pragma unroll
      for (int jd = 0; jd < 4; ++jd) {
        const float z = (oacc[i][jd][r] - mu) * rst * lnwv[jd] + lnbv[jd];
        const float y = z / (1.0f + expf(-z));   // SiLU
        const int f = jd * 16 + l15;
        scrw[sl * 64 + ((((f >> 3) + (sl >> 2)) & 7) << 3) + (f & 7)] = f2bf(y);
      }
    }
  // pane stores: 4 x 1KB fully-coalesced bursts into packed yb
  const int tile0 = b * 128 + c * 8 + w * 2;
#pragma unroll
  for (int tt = 0; tt < 2; ++tt)
#pragma unroll
    for (int kcl = 0; kcl < 2; ++kcl) {
      const int row = tt * 16 + l15;
      const int slot = ((kcl * 4 + quad) + (row >> 2)) & 7;
      short8 vv = *(const short8*)&scrw[row * 64 + slot * 8];
      *(short8*)(yb + ((size_t)(tile0 + tt) * 32 + h * 2 + kcl) * 512 + lane * 8) = vv;
    }
}

// ---------------------------------------------------------------- launch
extern "C" void kernel_launch(void* const* d_in, const int* in_sizes, int n_in,
                              void* d_out, int out_size, void* d_ws, size_t ws_size,
                              hipStream_t stream) {
  const float* x   = (const float*)d_in[0];
  const float* Wq  = (const float*)d_in[1];
  const float* Wk  = (const float*)d_in[2];
  const float* Wv  = (const float*)d_in[3];
  const float* Wo  = (const float*)d_in[4];
  const float* lnw = (const float*)d_in[5];
  const float* lnb = (const float*)d_in[6];
  float* out = (float*)d_out;

  char* ws = (char*)d_ws;
  u16* xbf  = (u16*)(ws + 0);         // 16 MB pane-packed x; reused as packed y
  u16* wqkv = (u16*)(ws + 16777216);  // 6 MB pane-packed — dead after QKV gemm
  u16* Sb   = (u16*)(ws + 16777216);  // 8 MB S panes — written after wqkv dead
  u16* qbuf = (u16*)(ws + 25165824);  // 16 MB q panes
  u16* kbuf = (u16*)(ws + 41943040);  // 16 MB k panes
  u16* vtb  = (u16*)(ws + 58720256);  // 16 MB v^T panes
  u16* wo   = (u16*)(ws + 75497472);  // 2 MB pane-packed
  float2* rtab = (float2*)(ws + 77594624);  // 512 KB
  u16* yb   = xbf;
  // d_out doubles as scratch until the final GEMM overwrites it entirely:
  u16* kwt  = (u16*)d_out;                          // 16 MB kwt panes
  float* Ubuf = (float*)((char*)d_out + 16777216);  // 16 MB fp32 chunk outer products

  prep_kernel<<<dim3(1024), dim3(256), 0, stream>>>(x, Wq, Wk, Wv, Wo, xbf, wqkv, wo,
                                                    rtab);
  gemm_bt<0><<<dim3(12, 64), dim3(256), 0, stream>>>(xbf, wqkv, 1024, qbuf, kbuf, vtb,
                                                     kwt, rtab, nullptr);
  kvchunk_kernel<<<dim3(16, 64), dim3(256), 0, stream>>>(kwt, vtb, Ubuf);
  scan_kernel<<<dim3(64), dim3(256), 0, stream>>>(Ubuf, Sb);
  attn_chunk_kernel<<<dim3(16, 64), dim3(256), 0, stream>>>(qbuf, kbuf, vtb, Sb, lnw,
                                                            lnb, yb);
  gemm_bt<1><<<dim3(4, 128), dim3(256), 0, stream>>>(yb, wo, 1024, nullptr, nullptr,
                                                     nullptr, nullptr, nullptr, out);
}

// Round 10
// 236.345 us; speedup vs baseline: 1.0298x; 1.0298x over previous
//
#include <hip/hip_runtime.h>
#include <math.h>

typedef unsigned short u16;
typedef __attribute__((ext_vector_type(8))) short short8;   // 8 bf16 operand frag (4 VGPRs)
typedef __attribute__((ext_vector_type(4))) float floatx4;  // 4 fp32 accum frag

#define LDS_AS(p) ((__attribute__((address_space(3))) void*)(p))
#define GLB_AS(p) ((const __attribute__((address_space(1))) void*)(p))

__device__ __forceinline__ u16 f2bf(float f) {
  unsigned int u = __float_as_uint(f);
  u += 0x7fffu + ((u >> 16) & 1u);          // round-to-nearest-even
  return (u16)(u >> 16);
}

__device__ __forceinline__ void gld16(const void* g, void* l) {
  // async global->LDS, 16B/lane, dest = wave-uniform base + lane*16
  __builtin_amdgcn_global_load_lds(GLB_AS(g), LDS_AS(l), 16, 0, 0);
}

__device__ __forceinline__ floatx4 mfma16(short8 a, short8 b, floatx4 c) {
  return __builtin_amdgcn_mfma_f32_16x16x32_bf16(a, b, c, 0, 0, 0);
}

// PANE CONVENTION: a pane is 512 u16 = [16 rows][32 cols] in MFMA lane order,
// element (lane,j) = src[row0 + (lane&15)][col0 + (lane>>4)*8 + j]. One
// gld16/store per pane is a single contiguous 1KB burst. Tensors:
//   qb,kb : [bh][chk16][nsub8][kk2][512]   kwt: [bh][chk16][m4][kst4][512]
//   vtb   : [bh][chk16][jd4][kst4][512]    Sb : [bh][chk16][nd4][kk2][512]

// ---------------------------------------------------------------- fused prep
__global__ void prep_kernel(const float* __restrict__ x, const float* __restrict__ Wq,
                            const float* __restrict__ Wk, const float* __restrict__ Wv,
                            const float* __restrict__ Wo, u16* __restrict__ xp,
                            u16* __restrict__ wqkvp, u16* __restrict__ wop,
                            float2* __restrict__ rtab) {
  int i = blockIdx.x * blockDim.x + threadIdx.x;
  const int str = gridDim.x * blockDim.x;
  for (; i < 3211264; i += str) {
    if (i < 3145728) {
      // one ushort4 (4 dest u16, same lane, j-half jh) per iteration
      int U; u16* d;
      const float* s;
      if (i < 2097152)      { U = i;           d = xp;    s = x;  }
      else if (i < 2883584) { U = i - 2097152; d = wqkvp; s = nullptr; }
      else                  { U = i - 2883584; d = wop;   s = Wo; }
      const int tile = U >> 12;            // 16-row tile
      const int kc   = (U >> 7) & 31;      // 32-col chunk
      const int lane = (U >> 1) & 63;
      const int jh   = U & 1;
      const int scol = kc * 32 + (lane >> 4) * 8 + jh * 4;
      int srow = tile * 16 + (lane & 15);
      if (s == nullptr) {                  // stacked Wq/Wk/Wv rows
        const int sel = srow >> 10;
        srow &= 1023;
        s = (sel == 0) ? Wq : (sel == 1) ? Wk : Wv;
      }
      float4 v = ((const float4*)s)[srow * 256 + (scol >> 2)];
      ushort4 o;
      o.x = f2bf(v.x); o.y = f2bf(v.y); o.z = f2bf(v.z); o.w = f2bf(v.w);
      ((ushort4*)d)[U] = o;
    } else {
      const int t = i - 3145728;              // 0..65535
      const int seq = t >> 5, dh = t & 31;
      const float freq = exp2f(-(float)dh * 0.42863594770f); // log2(1e4)/31
      float sn, cs;
      __sincosf((float)seq * freq, &sn, &cs);
      rtab[t] = make_float2(sn, cs);
    }
  }
}

// ---------------------------------------------------------------- GEMM C = A * B^T
// Geometry r7/8-verified (128x256 QKV / BM=64 out, BK=32, 4 waves, 3x24KB
// bufs, depth-2, counted vmcnt, 2 blocks/CU, pane-packed operands), r9 phase
// ordering (ds_read -> stage -> vmcnt -> BAR -> lgkm -> MFMA -> BAR). QKV is
// at the 2-phase structural ceiling (~690 TF) -- FROZEN.
template <int EPI>
__global__ __launch_bounds__(256, 2)
void gemm_bt(const u16* __restrict__ A, const u16* __restrict__ Bw, int K,
             u16* __restrict__ qb, u16* __restrict__ kb, u16* __restrict__ vtb,
             u16* __restrict__ kwt, const float2* __restrict__ rtab,
             float* __restrict__ outp) {
  constexpr int AP   = (EPI == 0) ? 8 : 4;        // A panes per buffer
  constexpr int BUFU = (AP + 16) * 512;           // u16 per buffer
  constexpr int AOFF = AP * 512;                  // B area offset in buffer
  constexpr int AI   = (EPI == 0) ? 8 : 4;        // acc rows (16-row frags)
  constexpr int IH   = (EPI == 0) ? 2 : 1;        // epilogue 64-row halves
  __shared__ __align__(16) u16 smem[3 * 12288];   // 72 KB worst case
  const int tid = threadIdx.x;
  const int w = tid >> 6, lane = tid & 63;        // 4 waves
  const int quad = lane >> 4, l15 = lane & 15;
  const int m0 = blockIdx.y * (EPI == 0 ? 128 : 64), n0 = blockIdx.x * 256;

  const size_t tsz = (size_t)(K >> 5) * 512;       // u16 per packed 16-row tile
  const u16* A0 = A + ((size_t)(m0 >> 4) + (EPI == 0 ? 2 * w : w)) * tsz + lane * 8;
  const u16* A1 = A0 + tsz;                        // used only when EPI==0
  const u16* Bb = Bw + ((size_t)(n0 >> 4) + 4 * w) * tsz + lane * 8;

  auto stage = [&](int buf, int kc) {
    const int nb = buf * BUFU;
    gld16(A0 + (size_t)kc * 512, &smem[nb + (EPI == 0 ? 2 * w : w) * 512]);
    if constexpr (EPI == 0)
      gld16(A1 + (size_t)kc * 512, &smem[nb + (2 * w + 1) * 512]);
#pragma unroll
    for (int e = 0; e < 4; ++e)
      gld16(Bb + (size_t)e * tsz + (size_t)kc * 512,
            &smem[nb + AOFF + (4 * w + e) * 512]);
  };

  floatx4 acc[AI][4] = {};
  const int NT = K >> 5;                      // 32 K-steps (pane index = step)

  stage(0, 0);                                // prologue: tiles 0,1 in flight
  stage(1, 1);
  if constexpr (EPI == 0)                     // tile 0 landed; tile 1 in flight
    asm volatile("s_waitcnt vmcnt(6)" ::: "memory");
  else
    asm volatile("s_waitcnt vmcnt(5)" ::: "memory");
  __builtin_amdgcn_s_barrier();               // publish tile 0

  int cur = 0, stg = 2;
  for (int t = 0; t < NT; ++t) {
    // --- phase: ds_read current tile (issued pre-barrier, consumed post-lgkm)
    const u16* Ap = &smem[cur * BUFU];
    const u16* Bp = Ap + AOFF;
    short8 a[AI], b[4];
#pragma unroll
    for (int i = 0; i < AI; ++i)
      a[i] = *(const short8*)&Ap[i * 512 + lane * 8];
#pragma unroll
    for (int j = 0; j < 4; ++j)
      b[j] = *(const short8*)&Bp[(w * 4 + j) * 512 + lane * 8];
    // --- stage tile t+2 (depth-2), then counted wait guarding tile t+1
    if (t + 2 < NT) {
      stage(stg, t + 2);
      if constexpr (EPI == 0)
        asm volatile("s_waitcnt vmcnt(6)" ::: "memory");
      else
        asm volatile("s_waitcnt vmcnt(5)" ::: "memory");
    } else {
      asm volatile("s_waitcnt vmcnt(0)" ::: "memory");
    }
    __builtin_amdgcn_s_barrier();             // BAR1: publish t+1, align waves
    asm volatile("s_waitcnt lgkmcnt(0)" ::: "memory");
    __builtin_amdgcn_sched_barrier(0);        // rule #18: pin MFMA after lgkm
    __builtin_amdgcn_s_setprio(1);
#pragma unroll
    for (int i = 0; i < AI; ++i)
#pragma unroll
      for (int j = 0; j < 4; ++j)
        acc[i][j] = mfma16(a[i], b[j], acc[i][j]);
    __builtin_amdgcn_s_setprio(0);
    asm volatile("" ::: "memory");
    __builtin_amdgcn_s_barrier();             // BAR2: close phase
    asm volatile("" ::: "memory");
    cur = (cur == 2) ? 0 : cur + 1;
    stg = (stg == 2) ? 0 : stg + 1;
  }

  // staging LDS now dead -> 8 KB wave-private scratch (4 waves x 8 KB = 32 KB)
  u16* scr = &smem[w * 4096];

  const int ncb = n0 + w * 64;

#pragma unroll
  for (int ih = 0; ih < IH; ++ih) {
    const int mrb = m0 + ih * 64;

    if (EPI == 0) {
      const int which = n0 >> 10;       // 0:q 1:k 2:v  (256-col blocks, 4 per matrix)
      const int c1024 = ncb & 1023;
      const int bidx = mrb >> 11;
      const int hh = c1024 >> 6;        // wave-tile col-quarter = one head (64 d)
      const int seq0 = mrb & 2047;
      const int chk = seq0 >> 7;        // 128-seq chunk; s-in-chunk base = ih*64

      if (which < 2) {
        // ---- pass 1: q/k, RoPE applied, rotated d-chunks in scr [sl][d-rot]
#pragma unroll
        for (int j = 0; j < 4; ++j) {
          const int d = j * 16 + l15;
          const int dc = d >> 3, dl = d & 7;
#pragma unroll
          for (int i = 0; i < 4; ++i)
#pragma unroll
            for (int r = 0; r < 4; ++r) {
              const int sl = i * 16 + quad * 4 + r;
              const int seq = seq0 + sl;
              const float v = acc[ih * 4 + i][j][r];
              const float p = __shfl_xor(v, 1, 64);
              const float2 sc = rtab[(d >> 1) + seq * 32];
              const float res = (d & 1) ? (v * sc.y + p * sc.x) : (v * sc.y - p * sc.x);
              scr[sl * 64 + (((dc + (sl >> 2)) & 7) << 3) + dl] = f2bf(res);
            }
        }
        // pane stores: [bh][chk][nsub][kk][512], 8 x 1KB contiguous bursts
        u16* dst = ((which == 0) ? qb : kb) +
                   (((size_t)(bidx * 16 + hh) * 16 + chk) << 13);
#pragma unroll
        for (int nl = 0; nl < 4; ++nl)
#pragma unroll
          for (int kk2 = 0; kk2 < 2; ++kk2) {
            const int slr = nl * 16 + l15;
            const int slot = ((kk2 * 4 + quad) + (slr >> 2)) & 7;
            short8 vv = *(const short8*)&scr[slr * 64 + slot * 8];
            *(short8*)(dst + (((ih * 4 + nl) * 2 + kk2) * 512) + lane * 8) = vv;
          }
        if (which == 1) {
          // ---- pass 2: kwt panes [bh][chk][m][kst][512], decay-weighted
          const float l2h = __log2f(1.0f - exp2f(-(float)(5 + hh)));
#pragma unroll
          for (int j = 0; j < 4; ++j) {
            const int d = j * 16 + l15;
#pragma unroll
            for (int i = 0; i < 4; ++i) {
              ushort4 pk;
#pragma unroll
              for (int r = 0; r < 4; ++r) {
                const int sl = i * 16 + quad * 4 + r;
                const int seq = seq0 + sl;
                const float v = acc[ih * 4 + i][j][r];
                const float p = __shfl_xor(v, 1, 64);
                const float2 sc = rtab[(d >> 1) + seq * 32];
                const float res = (d & 1) ? (v * sc.y + p * sc.x) : (v * sc.y - p * sc.x);
                const float wgt = exp2f((float)(127 - (seq & 127)) * l2h);
                ((u16*)&pk)[r] = f2bf(res * wgt);
              }
              *(ushort4*)&scr[d * 64 + ((i * 16 + quad * 4 + 8 * (d & 7)) & 63)] = pk;
            }
          }
          u16* dw = kwt + (((size_t)(bidx * 16 + hh) * 16 + chk) << 13);
#pragma unroll
          for (int m = 0; m < 4; ++m)
#pragma unroll
            for (int ks2 = 0; ks2 < 2; ++ks2) {
              const int dr = m * 16 + l15;
              const int col = ((ks2 * 32 + quad * 8) + 8 * (dr & 7)) & 63;
              short8 vv = *(const short8*)&scr[dr * 64 + col];
              *(short8*)(dw + ((m * 4 + ih * 2 + ks2) * 512) + lane * 8) = vv;
            }
        }
      } else {
        // ---- v transposed panes [bh][chk][jd][kst][512]
#pragma unroll
        for (int j = 0; j < 4; ++j) {
          const int d = j * 16 + l15;
#pragma unroll
          for (int i = 0; i < 4; ++i) {
            ushort4 pk;
            pk.x = f2bf(acc[ih * 4 + i][j][0]);
            pk.y = f2bf(acc[ih * 4 + i][j][1]);
            pk.z = f2bf(acc[ih * 4 + i][j][2]);
            pk.w = f2bf(acc[ih * 4 + i][j][3]);
            *(ushort4*)&scr[d * 64 + ((i * 16 + quad * 4 + 8 * (d & 7)) & 63)] = pk;
          }
        }
        u16* dh = vtb + (((size_t)(bidx * 16 + hh) * 16 + chk) << 13);
#pragma unroll
        for (int m = 0; m < 4; ++m)
#pragma unroll
          for (int ks2 = 0; ks2 < 2; ++ks2) {
            const int dr = m * 16 + l15;
            const int col = ((ks2 * 32 + quad * 8) + 8 * (dr & 7)) & 63;
            short8 vv = *(const short8*)&scr[dr * 64 + col];
            *(short8*)(dh + ((m * 4 + ih * 2 + ks2) * 512) + lane * 8) = vv;
          }
      }
    } else {
      // ---- fp32 out via LDS quarter-tiles (16 rows x pitch 65), full-line stores
      float* scrf = (float*)scr;                  // 8 KB = 2048 fp32
      const int lr4 = lane >> 4, lc16 = lane & 15;
#pragma unroll
      for (int p = 0; p < 4; ++p) {               // p = row-group (acc i index)
#pragma unroll
        for (int j = 0; j < 4; ++j)
#pragma unroll
          for (int r = 0; r < 4; ++r)
            scrf[(quad * 4 + r) * 65 + j * 16 + l15] = acc[p][j][r];
#pragma unroll
        for (int cch = 0; cch < 4; ++cch) {       // 4 stores x 4 rows x 256 B
          const int rr = cch * 4 + lr4;
          float4 vv = *(const float4*)&scrf[rr * 65 + lc16 * 4];
          *(float4*)&outp[(size_t)(mrb + p * 16 + rr) * 1024 + ncb + lc16 * 4] = vv;
        }
      }
    }
  }
}

// ---------------------------------------------------------------- fused KV-chunk + scan
// ROUND-10: kvchunk+scan fused; U buffer (16.7 MB fp32 write + uncoalesced
// re-read) eliminated. Key: kvchunk's MFMA acc layout acc[m][r] =
// U[dk=m*16+quad*4+r][dv=w*16+l15] is elementwise-compatible with the scan
// recurrence (independent per (dk,dv)) -> scan state S[m][r] lives in 16
// registers in the SAME layout; no transpose needed. Per bh-block: 16 chunks
// serially, double-buffered pane staging (2 x 32 KB LDS, counted vmcnt(8)),
// 16 MFMA + 16 FMA per chunk; Sb[c] (pre-update state) written as 4 coalesced
// ushort4 stores per thread. Pane mapping derived + checked element-wise vs
// the r8 scan-writer / attn-reader pair: nd=w, kk=m>>1,
// lane_p=((m&1)*2+(quad>>1))*16+l15, j=(quad&1)*4+r
//   => dv = w*16+l15 (ok), dk = m*16+quad*4+r (ok).
__global__ __launch_bounds__(256, 2)
void kvscan_kernel(const u16* __restrict__ kwt, const u16* __restrict__ vtb,
                   u16* __restrict__ Sb) {
  __shared__ __align__(16) u16 kls[2][16 * 512];   // 32 KB
  __shared__ __align__(16) u16 vls[2][16 * 512];   // 32 KB
  const int bh = blockIdx.x;
  const int tid = threadIdx.x, w = tid >> 6, lane = tid & 63;
  const int quad = lane >> 4, l15 = lane & 15;
  const int h = bh & 15;
  const float l2 = __log2f(1.0f - exp2f(-(float)(5 + h)));
  const float lamL = exp2f(128.0f * l2);

  const u16* kg = kwt + ((size_t)bh << 17);   // bh * 16 chunks * 8192 u16
  const u16* vg = vtb + ((size_t)bh << 17);
  u16* sbase = Sb + ((size_t)bh << 16);       // bh * 16 chunks * 4096 u16

  auto stage = [&](int buf, int c) {
    const u16* kc = kg + ((size_t)c << 13);
    const u16* vc = vg + ((size_t)c << 13);
#pragma unroll
    for (int rg = 0; rg < 4; ++rg) {
      const int rid = w * 4 + rg;             // pane idx == LDS region idx
      gld16(kc + rid * 512 + lane * 8, &kls[buf][rid * 512]);
      gld16(vc + rid * 512 + lane * 8, &vls[buf][rid * 512]);
    }
  };

  float S[4][4] = {};   // S[m][r]: dk = m*16+quad*4+r, dv = w*16+l15

  stage(0, 0);
  int buf = 0;
  for (int c = 0; c < 16; ++c) {
    if (c + 1 < 16) {
      stage(buf ^ 1, c + 1);                  // 16 outstanding/wave
      asm volatile("s_waitcnt vmcnt(8)" ::: "memory");  // chunk c landed
    } else {
      asm volatile("s_waitcnt vmcnt(0)" ::: "memory");
    }
    __builtin_amdgcn_s_barrier();
    asm volatile("" ::: "memory");

    // ---- write Sb[c] = state BEFORE chunk c (matches old scan semantics)
    u16* sp = sbase + ((size_t)c << 12);
#pragma unroll
    for (int m = 0; m < 4; ++m) {
      ushort4 pk;
#pragma unroll
      for (int r = 0; r < 4; ++r) ((u16*)&pk)[r] = f2bf(S[m][r]);
      const int lanep = ((m & 1) * 2 + (quad >> 1)) * 16 + l15;
      *(ushort4*)(sp + (w * 2 + (m >> 1)) * 512 + lanep * 8 + (quad & 1) * 4) = pk;
    }

    // ---- U_c via MFMA (identical math to old kvchunk)
    floatx4 acc[4] = {};
#pragma unroll
    for (int kst = 0; kst < 4; ++kst) {
      short8 bf = *(const short8*)&vls[buf][(w * 4 + kst) * 512 + lane * 8];
#pragma unroll
      for (int m = 0; m < 4; ++m) {
        short8 af = *(const short8*)&kls[buf][(m * 4 + kst) * 512 + lane * 8];
        acc[m] = mfma16(af, bf, acc[m]);
      }
    }
#pragma unroll
    for (int m = 0; m < 4; ++m)
#pragma unroll
      for (int r = 0; r < 4; ++r)
        S[m][r] = lamL * S[m][r] + acc[m][r];

    asm volatile("" ::: "memory");
    __builtin_amdgcn_s_barrier();             // protect buf before overwrite
    buf ^= 1;
  }
}

// ---------------------------------------------------------------- chunked attention
__global__ __launch_bounds__(256, 2)
void attn_chunk_kernel(const u16* __restrict__ qb, const u16* __restrict__ kb,
                       const u16* __restrict__ vtb, const u16* __restrict__ Sb,
                       const float* __restrict__ lnw, const float* __restrict__ lnb,
                       u16* __restrict__ yb) {
  __shared__ __align__(16) u16 kls[16 * 512];
  __shared__ __align__(16) u16 vls[16 * 512];
  __shared__ __align__(16) u16 Sls[8 * 512];
  __shared__ __align__(16) u16 pls[4 * 32 * 40];   // per-wave quarter P strip, pitch 40

  const int c = blockIdx.x, bh = blockIdx.y, h = bh & 15;
  const int tid = threadIdx.x;
  const int w = tid >> 6, lane = tid & 63, quad = lane >> 4, l15 = lane & 15;
  const float l2 = __log2f(1.0f - exp2f(-(float)(5 + h)));

  // pane-contiguous staging: pane idx == LDS region idx, 1KB burst each
  const u16* kg = kb + (((size_t)bh * 16 + c) << 13);
  const u16* vg = vtb + (((size_t)bh * 16 + c) << 13);
  const u16* Sg = Sb + (((size_t)bh * 16 + c) << 12);
#pragma unroll
  for (int rg = 0; rg < 4; ++rg) {
    const int kid = w * 4 + rg;
    gld16(kg + kid * 512 + lane * 8, &kls[kid * 512]);
    gld16(vg + kid * 512 + lane * 8, &vls[kid * 512]);
  }
#pragma unroll
  for (int e = 0; e < 2; ++e) {
    const int rid = w * 2 + e;
    gld16(Sg + rid * 512 + lane * 8, &Sls[rid * 512]);
  }

  // q fragments: direct pane register loads (contiguous 1KB per fragment)
  short8 qf[2][2];
  {
    const u16* qp = qb + (((size_t)bh * 16 + c) << 13);
#pragma unroll
    for (int i = 0; i < 2; ++i)
#pragma unroll
      for (int kk = 0; kk < 2; ++kk)
        qf[i][kk] = *(const short8*)(qp + (((w * 2 + i) * 2 + kk) * 512) + lane * 8);
  }
  float lnwv[4], lnbv[4];
#pragma unroll
  for (int jd = 0; jd < 4; ++jd) {
    lnwv[jd] = lnw[jd * 16 + l15];
    lnbv[jd] = lnb[jd * 16 + l15];
  }
  __syncthreads();

  // ---- intra scores: S = q k^T (32 s-rows x 128 t-cols)
  floatx4 sacc[2][8] = {};
#pragma unroll
  for (int kk = 0; kk < 2; ++kk) {
    short8 bf[8];
#pragma unroll
    for (int j = 0; j < 8; ++j)
      bf[j] = *(const short8*)&kls[(j * 2 + kk) * 512 + lane * 8];
#pragma unroll
    for (int i = 0; i < 2; ++i)
#pragma unroll
      for (int j = 0; j < 8; ++j)
        sacc[i][j] = mfma16(qf[i][kk], bf[j], sacc[i][j]);
  }

  // ---- cross: oacc = q . S_state^T, scaled by lambda^{s_loc+1}
  floatx4 oacc[2][4] = {};
#pragma unroll
  for (int kk = 0; kk < 2; ++kk)
#pragma unroll
    for (int nd = 0; nd < 4; ++nd) {
      short8 sf = *(const short8*)&Sls[(nd * 2 + kk) * 512 + lane * 8];
#pragma unroll
      for (int i = 0; i < 2; ++i)
        oacc[i][nd] = mfma16(qf[i][kk], sf, oacc[i][nd]);
    }
  float rowf[8];
#pragma unroll
  for (int i = 0; i < 2; ++i)
#pragma unroll
    for (int r = 0; r < 4; ++r)
      rowf[i * 4 + r] = exp2f((float)(w * 32 + i * 16 + quad * 4 + r) * l2);
  const float lam1 = exp2f(l2);
#pragma unroll
  for (int i = 0; i < 2; ++i)
#pragma unroll
    for (int nd = 0; nd < 4; ++nd)
#pragma unroll
      for (int r = 0; r < 4; ++r)
        oacc[i][nd][r] *= rowf[i * 4 + r] * lam1;   // lambda^{s_loc+1}

  // ---- intra PV with masked/decayed P, quarter-strip at a time
  float colf[8];
#pragma unroll
  for (int j = 0; j < 8; ++j) colf[j] = exp2f(-(float)(j * 16 + l15) * l2);
  u16* pw = &pls[w * 1280];
#pragma unroll
  for (int kst = 0; kst < 4; ++kst) {
#pragma unroll
    for (int jl = 0; jl < 2; ++jl) {
      const int j = kst * 2 + jl;
#pragma unroll
      for (int i = 0; i < 2; ++i)
#pragma unroll
        for (int r = 0; r < 4; ++r) {
          const int srow = i * 16 + quad * 4 + r;            // wave-local s
          const int dlt = (w * 32 + srow) - (j * 16 + l15);  // causal in-chunk
          const float v =
              (dlt >= 0) ? sacc[i][j][r] * rowf[i * 4 + r] * colf[j] : 0.0f;
          pw[srow * 40 + jl * 16 + l15] = f2bf(v);
        }
    }
    short8 pf[2], vf[4];
#pragma unroll
    for (int i = 0; i < 2; ++i)
      pf[i] = *(const short8*)&pw[(i * 16 + l15) * 40 + quad * 8];
#pragma unroll
    for (int jd = 0; jd < 4; ++jd)
      vf[jd] = *(const short8*)&vls[(jd * 4 + kst) * 512 + lane * 8];
#pragma unroll
    for (int i = 0; i < 2; ++i)
#pragma unroll
      for (int jd = 0; jd < 4; ++jd)
        oacc[i][jd] = mfma16(pf[i], vf[jd], oacc[i][jd]);
  }

  // ---- LayerNorm(64) + SiLU -> y, PANE-PACKED via LDS transpose.
  __syncthreads();
  u16* scrw = &kls[w * 2048];                  // 32 rows x 64 f, rotated chunks
  const int b = bh >> 4;
#pragma unroll
  for (int i = 0; i < 2; ++i)
#pragma unroll
    for (int r = 0; r < 4; ++r) {
      float sum = 0.f, ssq = 0.f;
#pragma unroll
      for (int jd = 0; jd < 4; ++jd) {
        const float v = oacc[i][jd][r];
        sum += v;
        ssq += v * v;
      }
#pragma unroll
      for (int off = 1; off < 16; off <<= 1) {
        sum += __shfl_xor(sum, off, 64);
        ssq += __shfl_xor(ssq, off, 64);
      }
      const float mu = sum * (1.0f / 64.0f);
      const float var = ssq * (1.0f / 64.0f) - mu * mu;
      const float rst = rsqrtf(var + 1e-5f);
      const int sl = i * 16 + quad * 4 + r;    // wave-local token row
#pragma unroll
      for (int jd = 0; jd < 4; ++jd) {
        const float z = (oacc[i][jd][r] - mu) * rst * lnwv[jd] + lnbv[jd];
        const float y = z / (1.0f + expf(-z));   // SiLU
        const int f = jd * 16 + l15;
        scrw[sl * 64 + ((((f >> 3) + (sl >> 2)) & 7) << 3) + (f & 7)] = f2bf(y);
      }
    }
  // pane stores: 4 x 1KB fully-coalesced bursts into packed yb
  const int tile0 = b * 128 + c * 8 + w * 2;
#pragma unroll
  for (int tt = 0; tt < 2; ++tt)
#pragma unroll
    for (int kcl = 0; kcl < 2; ++kcl) {
      const int row = tt * 16 + l15;
      const int slot = ((kcl * 4 + quad) + (row >> 2)) & 7;
      short8 vv = *(const short8*)&scrw[row * 64 + slot * 8];
      *(short8*)(yb + ((size_t)(tile0 + tt) * 32 + h * 2 + kcl) * 512 + lane * 8) = vv;
    }
}

// ---------------------------------------------------------------- launch
extern "C" void kernel_launch(void* const* d_in, const int* in_sizes, int n_in,
                              void* d_out, int out_size, void* d_ws, size_t ws_size,
                              hipStream_t stream) {
  const float* x   = (const float*)d_in[0];
  const float* Wq  = (const float*)d_in[1];
  const float* Wk  = (const float*)d_in[2];
  const float* Wv  = (const float*)d_in[3];
  const float* Wo  = (const float*)d_in[4];
  const float* lnw = (const float*)d_in[5];
  const float* lnb = (const float*)d_in[6];
  float* out = (float*)d_out;

  char* ws = (char*)d_ws;
  u16* xbf  = (u16*)(ws + 0);         // 16 MB pane-packed x; reused as packed y
  u16* wqkv = (u16*)(ws + 16777216);  // 6 MB pane-packed — dead after QKV gemm
  u16* Sb   = (u16*)(ws + 16777216);  // 8 MB S panes — written after wqkv dead
  u16* qbuf = (u16*)(ws + 25165824);  // 16 MB q panes
  u16* kbuf = (u16*)(ws + 41943040);  // 16 MB k panes
  u16* vtb  = (u16*)(ws + 58720256);  // 16 MB v^T panes
  u16* wo   = (u16*)(ws + 75497472);  // 2 MB pane-packed
  float2* rtab = (float2*)(ws + 77594624);  // 512 KB
  u16* yb   = xbf;
  // d_out doubles as scratch until the final GEMM overwrites it entirely:
  u16* kwt  = (u16*)d_out;                          // 16 MB kwt panes

  prep_kernel<<<dim3(1024), dim3(256), 0, stream>>>(x, Wq, Wk, Wv, Wo, xbf, wqkv, wo,
                                                    rtab);
  gemm_bt<0><<<dim3(12, 64), dim3(256), 0, stream>>>(xbf, wqkv, 1024, qbuf, kbuf, vtb,
                                                     kwt, rtab, nullptr);
  kvscan_kernel<<<dim3(64), dim3(256), 0, stream>>>(kwt, vtb, Sb);
  attn_chunk_kernel<<<dim3(16, 64), dim3(256), 0, stream>>>(qbuf, kbuf, vtb, Sb, lnw,
                                                            lnb, yb);
  gemm_bt<1><<<dim3(4, 128), dim3(256), 0, stream>>>(yb, wo, 1024, nullptr, nullptr,
                                                     nullptr, nullptr, nullptr, out);
}